// Round 10
// baseline (249.417 us; speedup 1.0000x reference)
//
#include <hip/hip_runtime.h>

#define NN   100000
#define NE   1600000
#define DIN  128
#define DH   64
#define DOUT 128
#define NG   512

#define NB   391     // dst buckets of 256 nodes: ceil(NN/256)
#define EPB  6250    // edges per scatter block: NE/256
#define CAP  5120    // padded bucket capacity (verified sufficient in round 8/9)

typedef short short8 __attribute__((ext_vector_type(8)));
typedef float floatx4 __attribute__((ext_vector_type(4)));

__device__ __forceinline__ unsigned short f2bf(float f) {
  unsigned b = __float_as_uint(f);
  b += 0x7FFF + ((b >> 16) & 1);          // round-to-nearest-even
  return (unsigned short)(b >> 16);
}
__device__ __forceinline__ float bflo(unsigned u) {   // low 16 bits -> float
  return __uint_as_float(u << 16);
}
__device__ __forceinline__ float bfhi(unsigned u) {   // high 16 bits -> float
  return __uint_as_float(u & 0xFFFF0000u);
}
__device__ __forceinline__ unsigned pack2(float a, float b) {
  return (unsigned)f2bf(a) | ((unsigned)f2bf(b) << 16);
}

// ---------- prep: cursor init (block 0) + weight split (1) + graph bounds (2) ----------
__global__ __launch_bounds__(256) void prep_kernel(
    int* __restrict__ gcur,
    const float* __restrict__ W1l, const float* __restrict__ W1r,
    short* __restrict__ wfrag, const int* __restrict__ batch,
    int* __restrict__ gs) {
  int b = blockIdx.x;
  if (b == 0) {                       // --- bucket cursors: base of each region ---
    for (int i = threadIdx.x; i < NB; i += 256) gcur[i] = i * CAP;
  } else if (b == 1) {                // --- weight split ---
    for (int i = threadIdx.x; i < DIN * DH; i += 256) {
      int k = i >> 6, n = i & 63;
      int kt = k >> 5, kin = k & 31;
      int lane = ((kin >> 3) << 4) | (n & 15);
      int j8 = kin & 7;
      int jt = n >> 4;
      float wl = W1l[i], wr = W1r[i];
      unsigned bl_ = __float_as_uint(wl);
      unsigned br_ = __float_as_uint(wr);
      short hl = (short)(bl_ >> 16);
      short hr = (short)(br_ >> 16);
      float rl = wl - __uint_as_float(bl_ & 0xFFFF0000u);
      float rr = wr - __uint_as_float(br_ & 0xFFFF0000u);
      short ll = (short)(__float_as_uint(rl) >> 16);
      short lr = (short)(__float_as_uint(rr) >> 16);
      int base0 = (((kt * 2 + 0) * 4 + jt) * 2) * 512 + lane * 8 + j8;
      int base1 = (((kt * 2 + 1) * 4 + jt) * 2) * 512 + lane * 8 + j8;
      wfrag[base0]       = hl;
      wfrag[base0 + 512] = ll;
      wfrag[base1]       = hr;
      wfrag[base1 + 512] = lr;
    }
  } else {                            // --- graph boundaries ---
    for (int g = threadIdx.x; g <= NG; g += 256) {
      if (g == NG) { gs[NG] = NN; continue; }
      int lo = 0, hi = NN;
      while (lo < hi) {
        int mid = (lo + hi) >> 1;
        if (batch[mid] < g) lo = mid + 1; else hi = mid;
      }
      gs[g] = lo;
    }
  }
}

// ---------- fused: slice-claim partA (blocks 0..255) + proj MFMA (256..1818) ----------
// partA: LDS hist -> 1 global atomic per (block,bucket) slice claim -> LDS-cursor
// scatter (verified round 9). proj: NO LDS, no barriers — B fragments read direct
// from L1/L2-hot wfrag (64 KB shared by all waves); 1 tile/wave for max TLP.
__global__ __launch_bounds__(256, 4) void proj_part_kernel(
    const int* __restrict__ src, const int* __restrict__ dst,
    int* __restrict__ gcur, int* __restrict__ part,
    const float* __restrict__ x, const short* __restrict__ wfrag,
    const float* __restrict__ b1, unsigned short* __restrict__ xlb,
    unsigned short* __restrict__ xrb) {
  __shared__ int sH[3 * NB];          // 4.7 KB (partA only)
  if (blockIdx.x < 256) {
    int* hist  = sH;                  // [NB]
    int* base_ = sH + NB;             // [NB]
    int* lcur  = sH + 2 * NB;         // [NB]
    for (int i = threadIdx.x; i < NB; i += 256) hist[i] = 0;
    __syncthreads();
    int start = blockIdx.x * EPB, end = start + EPB;
    for (int e = start + threadIdx.x; e < end; e += 256)
      atomicAdd(&hist[dst[e] >> 8], 1);               // LDS atomic
    __syncthreads();
    for (int i = threadIdx.x; i < NB; i += 256) {
      base_[i] = atomicAdd(&gcur[i], hist[i]);        // 1 global atomic / bucket
      lcur[i] = 0;
    }
    __syncthreads();
    for (int e = start + threadIdx.x; e < end; e += 256) {
      int d = dst[e], s = src[e];
      int bkt = d >> 8;
      int pos = base_[bkt] + atomicAdd(&lcur[bkt], 1);  // LDS atomic
      if (pos < (bkt + 1) * CAP)                        // overflow guard
        part[pos] = ((d & 255) << 17) | s;
    }
    return;
  }
  // --- proj: xl(bf16)=x@W1l, xr(bf16)=x@W1r+b1 — barrier-free, 1 tile/wave ---
  int wave = threadIdx.x >> 6;
  int lane = threadIdx.x & 63;
  int m = lane & 15, q = lane >> 4;
  int tile = (blockIdx.x - 256) * 4 + wave;
  bool act = tile < 6250;
  int tc = act ? tile : 6249;      // clamp: tail waves compute garbage, skip stores

  int r0 = tc * 16 + m;
  const float4* xa = (const float4*)x + (size_t)r0 * 32 + q * 2;
  const short8* wf = (const short8*)wfrag + lane;   // + unit*64 strides below

  floatx4 acc[8];
#pragma unroll
  for (int a = 0; a < 8; ++a) acc[a] = (floatx4){0.f, 0.f, 0.f, 0.f};

#pragma unroll
  for (int kt = 0; kt < 4; ++kt) {
    float4 p0 = xa[kt * 8];
    float4 p1 = xa[kt * 8 + 1];
    float af0[8] = {p0.x, p0.y, p0.z, p0.w, p1.x, p1.y, p1.z, p1.w};
    short8 ah, al;
#pragma unroll
    for (int e = 0; e < 8; ++e) {
      unsigned b0 = __float_as_uint(af0[e]);
      ah[e] = (short)(b0 >> 16);
      float lo0 = af0[e] - __uint_as_float(b0 & 0xFFFF0000u);
      al[e] = (short)(__float_as_uint(lo0) >> 16);
    }
#pragma unroll
    for (int mat = 0; mat < 2; ++mat) {
#pragma unroll
      for (int jt = 0; jt < 4; ++jt) {
        int unit = ((kt * 2 + mat) * 4 + jt) * 2;
        short8 bh = wf[unit * 64];        // wfrag + unit*1024B + lane*16B (L1/L2-hot)
        short8 bl = wf[unit * 64 + 64];
        floatx4 c = acc[mat * 4 + jt];
        c = __builtin_amdgcn_mfma_f32_16x16x32_bf16(ah, bh, c, 0, 0, 0);
        c = __builtin_amdgcn_mfma_f32_16x16x32_bf16(ah, bl, c, 0, 0, 0);
        c = __builtin_amdgcn_mfma_f32_16x16x32_bf16(al, bh, c, 0, 0, 0);
        acc[mat * 4 + jt] = c;
      }
    }
  }

  if (act) {
#pragma unroll
    for (int jt = 0; jt < 4; ++jt) {
      int j = jt * 16 + m;
      float bj = b1[j];
      floatx4 cl = acc[jt], cr = acc[4 + jt];
#pragma unroll
      for (int r = 0; r < 4; ++r) {
        int n0 = tile * 16 + q * 4 + r;
        xlb[(size_t)n0 * DH + j] = f2bf(cl[r]);
        xrb[(size_t)n0 * DH + j] = f2bf(cr[r] + bj);
      }
    }
  }
}

// ---------- radix pass B: per-bucket CSR (row_start + row_end + eidx) ----------
// (verified rounds 8/9: padded regions, explicit row_end)
__global__ __launch_bounds__(256) void bucket_csr_kernel(
    const int* __restrict__ part, const int* __restrict__ gcur,
    int* __restrict__ row_start, int* __restrict__ row_end,
    int* __restrict__ eidx) {
  int b = blockIdx.x, t = threadIdx.x;
  int ebeg = b * CAP;
  int cnt_b = gcur[b] - ebeg; if (cnt_b > CAP) cnt_b = CAP;
  int eend = ebeg + cnt_b;
  int nbase = b << 8;
  int nloc = NN - nbase; if (nloc > 256) nloc = 256;
  __shared__ int cntL[256];
  __shared__ int exclL[256];
  cntL[t] = 0;
  __syncthreads();
  for (int e = ebeg + t; e < eend; e += 256)
    atomicAdd(&cntL[part[e] >> 17], 1);
  __syncthreads();
  int c = cntL[t];
  exclL[t] = c;
  __syncthreads();
  for (int off = 1; off < 256; off <<= 1) {
    int v = (t >= off) ? exclL[t - off] : 0;
    __syncthreads();
    exclL[t] += v;
    __syncthreads();
  }
  int excl = exclL[t] - c;
  if (t < nloc) {
    row_start[nbase + t] = ebeg + excl;
    row_end[nbase + t]   = ebeg + excl + c;
  }
  cntL[t] = excl;                 // reuse as cursor
  __syncthreads();
  for (int e = ebeg + t; e < eend; e += 256) {
    int v = part[e];
    int pos = atomicAdd(&cntL[v >> 17], 1);
    eidx[ebeg + pos] = v & 0x1FFFF;
  }
}

// ---------- layer-1 mean aggregation via gather (+relu+root add) ----------
template <bool RELU_ADD>
__global__ __launch_bounds__(256) void gather_kernel(
    const uint4* __restrict__ feat4, const int* __restrict__ row_start,
    const int* __restrict__ row_end, const int* __restrict__ eidx,
    const uint4* __restrict__ xr4, uint4* __restrict__ out4) {
  int t = blockIdx.x * 256 + threadIdx.x;
  int node = t >> 3;
  if (node >= NN) return;
  int fl = t & 7;
  int rs = row_start[node], re = row_end[node];
  float a0 = 0.f, a1 = 0.f, a2 = 0.f, a3 = 0.f;
  float a4 = 0.f, a5 = 0.f, a6 = 0.f, a7 = 0.f;
  int k = rs;
  for (; k + 8 <= re; k += 8) {           // 8 uint4 loads in flight
    uint4 v[8];
#pragma unroll
    for (int u = 0; u < 8; ++u) v[u] = feat4[(size_t)eidx[k + u] * 8 + fl];
#pragma unroll
    for (int u = 0; u < 8; ++u) {
      a0 += bflo(v[u].x); a1 += bfhi(v[u].x);
      a2 += bflo(v[u].y); a3 += bfhi(v[u].y);
      a4 += bflo(v[u].z); a5 += bfhi(v[u].z);
      a6 += bflo(v[u].w); a7 += bfhi(v[u].w);
    }
  }
  for (; k + 2 <= re; k += 2) {
    uint4 v0 = feat4[(size_t)eidx[k] * 8 + fl];
    uint4 v1 = feat4[(size_t)eidx[k + 1] * 8 + fl];
    a0 += bflo(v0.x) + bflo(v1.x); a1 += bfhi(v0.x) + bfhi(v1.x);
    a2 += bflo(v0.y) + bflo(v1.y); a3 += bfhi(v0.y) + bfhi(v1.y);
    a4 += bflo(v0.z) + bflo(v1.z); a5 += bfhi(v0.z) + bfhi(v1.z);
    a6 += bflo(v0.w) + bflo(v1.w); a7 += bfhi(v0.w) + bfhi(v1.w);
  }
  if (k < re) {
    uint4 v = feat4[(size_t)eidx[k] * 8 + fl];
    a0 += bflo(v.x); a1 += bfhi(v.x);
    a2 += bflo(v.y); a3 += bfhi(v.y);
    a4 += bflo(v.z); a5 += bfhi(v.z);
    a6 += bflo(v.w); a7 += bfhi(v.w);
  }
  float inv = 1.0f / fmaxf((float)(re - rs), 1.0f);
  a0 *= inv; a1 *= inv; a2 *= inv; a3 *= inv;
  a4 *= inv; a5 *= inv; a6 *= inv; a7 *= inv;
  if (RELU_ADD) {
    uint4 r = xr4[(size_t)node * 8 + fl];
    a0 = fmaxf(a0 + bflo(r.x), 0.f); a1 = fmaxf(a1 + bfhi(r.x), 0.f);
    a2 = fmaxf(a2 + bflo(r.y), 0.f); a3 = fmaxf(a3 + bfhi(r.y), 0.f);
    a4 = fmaxf(a4 + bflo(r.z), 0.f); a5 = fmaxf(a5 + bfhi(r.z), 0.f);
    a6 = fmaxf(a6 + bflo(r.w), 0.f); a7 = fmaxf(a7 + bfhi(r.w), 0.f);
  }
  uint4 o;
  o.x = pack2(a0, a1);
  o.y = pack2(a2, a3);
  o.z = pack2(a4, a5);
  o.w = pack2(a6, a7);
  out4[(size_t)node * 8 + fl] = o;
}

// ---------- fused layer-2 gather + pool + final matmul: one block per graph ----------
__global__ __launch_bounds__(1024) void gather2_pool_kernel(
    const uint4* __restrict__ feat4,          // hb rows (bf16, 8x uint4/node)
    const int* __restrict__ row_start, const int* __restrict__ row_end,
    const int* __restrict__ eidx,
    const int* __restrict__ gs, const float* __restrict__ W2l,
    const float* __restrict__ W2r, const float* __restrict__ b2,
    float* __restrict__ out) {
  int g = blockIdx.x;
  int start = gs[g], end = gs[g + 1];
  int slot = threadIdx.x >> 3;        // 0..127 node-slot
  int fl   = threadIdx.x & 7;         // 16B feature chunk (feats fl*8..fl*8+7)
  float sm[8], sh[8];
#pragma unroll
  for (int i = 0; i < 8; ++i) { sm[i] = 0.f; sh[i] = 0.f; }

  for (int n = start + slot; n < end; n += 128) {
    int rs = row_start[n], re = row_end[n];
    float a0 = 0.f, a1 = 0.f, a2 = 0.f, a3 = 0.f;
    float a4 = 0.f, a5 = 0.f, a6 = 0.f, a7 = 0.f;
    int k = rs;
    for (; k + 4 <= re; k += 4) {       // 4 loads in flight
      uint4 v[4];
#pragma unroll
      for (int u = 0; u < 4; ++u) v[u] = feat4[(size_t)eidx[k + u] * 8 + fl];
#pragma unroll
      for (int u = 0; u < 4; ++u) {
        a0 += bflo(v[u].x); a1 += bfhi(v[u].x);
        a2 += bflo(v[u].y); a3 += bfhi(v[u].y);
        a4 += bflo(v[u].z); a5 += bfhi(v[u].z);
        a6 += bflo(v[u].w); a7 += bfhi(v[u].w);
      }
    }
    for (; k < re; ++k) {
      uint4 v = feat4[(size_t)eidx[k] * 8 + fl];
      a0 += bflo(v.x); a1 += bfhi(v.x);
      a2 += bflo(v.y); a3 += bfhi(v.y);
      a4 += bflo(v.z); a5 += bfhi(v.z);
      a6 += bflo(v.w); a7 += bfhi(v.w);
    }
    float inv = 1.0f / fmaxf((float)(re - rs), 1.0f);
    sm[0] += a0 * inv; sm[1] += a1 * inv; sm[2] += a2 * inv; sm[3] += a3 * inv;
    sm[4] += a4 * inv; sm[5] += a5 * inv; sm[6] += a6 * inv; sm[7] += a7 * inv;
    uint4 hv = feat4[(size_t)n * 8 + fl];       // root h for the h-sum
    sh[0] += bflo(hv.x); sh[1] += bfhi(hv.x);
    sh[2] += bflo(hv.y); sh[3] += bfhi(hv.y);
    sh[4] += bflo(hv.z); sh[5] += bfhi(hv.z);
    sh[6] += bflo(hv.w); sh[7] += bfhi(hv.w);
  }

  // reduce the 8 node-slot groups inside each wave (lane bits [5:3])
#pragma unroll
  for (int off = 8; off <= 32; off <<= 1) {
#pragma unroll
    for (int i = 0; i < 8; ++i) {
      sm[i] += __shfl_xor(sm[i], off);
      sh[i] += __shfl_xor(sh[i], off);
    }
  }

  __shared__ float redm[16][DH];
  __shared__ float redh[16][DH];
  int wv = threadIdx.x >> 6;
  int lane = threadIdx.x & 63;
  if (lane < 8) {
#pragma unroll
    for (int i = 0; i < 8; ++i) {
      redm[wv][lane * 8 + i] = sm[i];
      redh[wv][lane * 8 + i] = sh[i];
    }
  }
  __syncthreads();
  __shared__ float msL[DH], hsL[DH];
  if (threadIdx.x < DH) {
    float a = 0.f, b = 0.f;
#pragma unroll
    for (int w = 0; w < 16; ++w) { a += redm[w][threadIdx.x]; b += redh[w][threadIdx.x]; }
    msL[threadIdx.x] = a; hsL[threadIdx.x] = b;
  }
  __syncthreads();
  int j = threadIdx.x;
  if (j < DOUT) {
    float n_ = (float)(end - start);
    float acc = 0.f;
#pragma unroll 8
    for (int k = 0; k < DH; ++k)
      acc += msL[k] * W2l[k * DOUT + j] + hsL[k] * W2r[k * DOUT + j];
    out[g * DOUT + j] = (acc + n_ * b2[j]) / fmaxf(n_, 1.0f);
  }
}

extern "C" void kernel_launch(void* const* d_in, const int* in_sizes, int n_in,
                              void* d_out, int out_size, void* d_ws, size_t ws_size,
                              hipStream_t stream) {
  (void)in_sizes; (void)n_in; (void)out_size; (void)ws_size;
  const float* x   = (const float*)d_in[0];
  const float* W1l = (const float*)d_in[1];
  const float* W1r = (const float*)d_in[2];
  const float* b1  = (const float*)d_in[3];
  const float* W2l = (const float*)d_in[4];
  const float* W2r = (const float*)d_in[5];
  const float* b2  = (const float*)d_in[6];
  const int*   ei  = (const int*)d_in[7];
  const int*   batch = (const int*)d_in[8];
  const int* src = ei;            // edge_index[0, :]
  const int* dst = ei + NE;       // edge_index[1, :]
  float* out = (float*)d_out;

  char* ws = (char*)d_ws;
  unsigned short* xlb = (unsigned short*)(ws);            // 12,800,000 B
  unsigned short* hb  = (unsigned short*)(ws + 12800000); // 12,800,000 B
  unsigned short* xrb = (unsigned short*)(ws + 38400000); // 12,800,000 B
  int*  part      = (int*)(ws + 51200000);           //  8,007,680 B (NB*CAP*4)
  int*  gcur      = (int*)(ws + 59300000);           //      1,564 B
  int*  eidx      = (int*)(ws + 60000000);           //  8,007,680 B (padded)
  int*  row_start = (int*)(ws + 83200000);           //    400,000 B
  int*   gs       = (int*)(ws + 83600128);           //      2,052 B
  short* wfrag    = (short*)(ws + 83900032);         //     65,536 B
  int*  row_end   = (int*)(ws + 84000000);           //    400,000 B

  const int gBlocks = (NN * 8 + 255) / 256;          // 3125

  // prep: bucket cursors + weight split + graph bounds (3 tiny block roles)
  prep_kernel<<<3, 256, 0, stream>>>(gcur, W1l, W1r, wfrag, batch, gs);

  // slice-claim partA fused with barrier-free proj (1 tile/wave, no proj LDS)
  proj_part_kernel<<<256 + 1563, 256, 0, stream>>>(src, dst, gcur, part,
                                                   x, wfrag, b1, xlb, xrb);
  bucket_csr_kernel<<<NB, 256, 0, stream>>>(part, gcur, row_start, row_end, eidx);

  // layer 1 aggregation (+ relu + root add)
  gather_kernel<true><<<gBlocks, 256, 0, stream>>>(
      (const uint4*)xlb, row_start, row_end, eidx, (const uint4*)xrb, (uint4*)hb);

  // layer 2 aggregation fused with pool + final matmul (one block per graph)
  gather2_pool_kernel<<<NG, 1024, 0, stream>>>(
      (const uint4*)hb, row_start, row_end, eidx, gs, W2l, W2r, b2, out);
}

// Round 11
// 239.425 us; speedup vs baseline: 1.0417x; 1.0417x over previous
//
#include <hip/hip_runtime.h>

#define NN   100000
#define NE   1600000
#define DIN  128
#define DH   64
#define DOUT 128
#define NG   512

#define NB    391    // dst buckets of 256 nodes: ceil(NN/256)
#define PARTB 250    // partA blocks
#define EPB   6400   // edges per partA block (= NE/250; 25.6 KB, 16B-aligned)
#define CAP   5120   // padded bucket capacity (verified sufficient rounds 8/9)

typedef short short8 __attribute__((ext_vector_type(8)));
typedef float floatx4 __attribute__((ext_vector_type(4)));

__device__ __forceinline__ unsigned short f2bf(float f) {
  unsigned b = __float_as_uint(f);
  b += 0x7FFF + ((b >> 16) & 1);          // round-to-nearest-even
  return (unsigned short)(b >> 16);
}
__device__ __forceinline__ float bflo(unsigned u) {   // low 16 bits -> float
  return __uint_as_float(u << 16);
}
__device__ __forceinline__ float bfhi(unsigned u) {   // high 16 bits -> float
  return __uint_as_float(u & 0xFFFF0000u);
}
__device__ __forceinline__ unsigned pack2(float a, float b) {
  return (unsigned)f2bf(a) | ((unsigned)f2bf(b) << 16);
}

// ---------- prep: cursor init (block 0) + weight split (1) + graph bounds (2) ----------
__global__ __launch_bounds__(256) void prep_kernel(
    int* __restrict__ gcur,
    const float* __restrict__ W1l, const float* __restrict__ W1r,
    short* __restrict__ wfrag, const int* __restrict__ batch,
    int* __restrict__ gs) {
  int b = blockIdx.x;
  if (b == 0) {                       // --- bucket cursors: base of each region ---
    for (int i = threadIdx.x; i < NB; i += 256) gcur[i] = i * CAP;
  } else if (b == 1) {                // --- weight split ---
    for (int i = threadIdx.x; i < DIN * DH; i += 256) {
      int k = i >> 6, n = i & 63;
      int kt = k >> 5, kin = k & 31;
      int lane = ((kin >> 3) << 4) | (n & 15);
      int j8 = kin & 7;
      int jt = n >> 4;
      float wl = W1l[i], wr = W1r[i];
      unsigned bl_ = __float_as_uint(wl);
      unsigned br_ = __float_as_uint(wr);
      short hl = (short)(bl_ >> 16);
      short hr = (short)(br_ >> 16);
      float rl = wl - __uint_as_float(bl_ & 0xFFFF0000u);
      float rr = wr - __uint_as_float(br_ & 0xFFFF0000u);
      short ll = (short)(__float_as_uint(rl) >> 16);
      short lr = (short)(__float_as_uint(rr) >> 16);
      int base0 = (((kt * 2 + 0) * 4 + jt) * 2) * 512 + lane * 8 + j8;
      int base1 = (((kt * 2 + 1) * 4 + jt) * 2) * 512 + lane * 8 + j8;
      wfrag[base0]       = hl;
      wfrag[base0 + 512] = ll;
      wfrag[base1]       = hr;
      wfrag[base1 + 512] = lr;
    }
  } else {                            // --- graph boundaries ---
    for (int g = threadIdx.x; g <= NG; g += 256) {
      if (g == NG) { gs[NG] = NN; continue; }
      int lo = 0, hi = NN;
      while (lo < hi) {
        int mid = (lo + hi) >> 1;
        if (batch[mid] < g) lo = mid + 1; else hi = mid;
      }
      gs[g] = lo;
    }
  }
}

// ---------- fused: slice-claim partA (blocks 0..249) + proj MFMA (250..1031) ----------
// partA: int4 edge reads; LDS hist -> 1 global atomic per (block,bucket) slice
// claim -> LDS-cursor scatter. proj: round-9 verified 2-tile 2-stage LDS form.
__global__ __launch_bounds__(256, 4) void proj_part_kernel(
    const int* __restrict__ src, const int* __restrict__ dst,
    int* __restrict__ gcur, int* __restrict__ part,
    const float* __restrict__ x, const short* __restrict__ wfrag,
    const float* __restrict__ b1, unsigned short* __restrict__ xlb,
    unsigned short* __restrict__ xrb) {
  __shared__ short sB[16384];   // 32 KB (partA aliases as 3 int arrays of NB)
  if (blockIdx.x < PARTB) {
    int* hist  = (int*)sB;            // [NB]
    int* base_ = hist + NB;           // [NB]
    int* lcur  = hist + 2 * NB;       // [NB]   (4.7 KB total)
    for (int i = threadIdx.x; i < NB; i += 256) hist[i] = 0;
    __syncthreads();
    int start = blockIdx.x * EPB;
    const int4* d4 = (const int4*)(dst + start);   // 16B-aligned (start*4 % 16 == 0)
    const int4* s4 = (const int4*)(src + start);
    for (int i = threadIdx.x; i < EPB / 4; i += 256) {
      int4 d = d4[i];
      atomicAdd(&hist[d.x >> 8], 1);
      atomicAdd(&hist[d.y >> 8], 1);
      atomicAdd(&hist[d.z >> 8], 1);
      atomicAdd(&hist[d.w >> 8], 1);
    }
    __syncthreads();
    for (int i = threadIdx.x; i < NB; i += 256) {
      base_[i] = atomicAdd(&gcur[i], hist[i]);     // 1 global atomic / bucket
      lcur[i] = 0;
    }
    __syncthreads();
    for (int i = threadIdx.x; i < EPB / 4; i += 256) {
      int4 d = d4[i];
      int4 s = s4[i];
      int de[4] = {d.x, d.y, d.z, d.w};
      int se[4] = {s.x, s.y, s.z, s.w};
#pragma unroll
      for (int u = 0; u < 4; ++u) {
        int bkt = de[u] >> 8;
        int pos = base_[bkt] + atomicAdd(&lcur[bkt], 1);  // LDS atomic
        if (pos < (bkt + 1) * CAP)                        // overflow guard
          part[pos] = ((de[u] & 255) << 17) | se[u];
      }
    }
    return;
  }
  // --- proj: xl(bf16)=x@W1l, xr(bf16)=x@W1r+b1 (round-9 verified structure) ---
  int wave = threadIdx.x >> 6;
  int lane = threadIdx.x & 63;
  int m = lane & 15, q = lane >> 4;
  int tpair = (blockIdx.x - PARTB) * 4 + wave;
  int tile0 = tpair * 2, tile1 = tile0 + 1;
  bool act0 = tile0 < 6250;
  bool act1 = tile1 < 6250;
  int t0c = act0 ? tile0 : 6249;   // clamp: tail waves compute garbage, skip stores
  int t1c = act1 ? tile1 : 6249;

  int r0 = t0c * 16 + m;
  int r1 = t1c * 16 + m;
  const float4* xa = (const float4*)x + (size_t)r0 * 32 + q * 2;
  const float4* xb = (const float4*)x + (size_t)r1 * 32 + q * 2;

  floatx4 acc0[8], acc1[8];
#pragma unroll
  for (int a = 0; a < 8; ++a) {
    acc0[a] = (floatx4){0.f, 0.f, 0.f, 0.f};
    acc1[a] = (floatx4){0.f, 0.f, 0.f, 0.f};
  }

  const float4* wf4 = (const float4*)wfrag;
  float4* sB4 = (float4*)sB;

#pragma unroll 1              // keep rolled: bounds VGPR, prevents load hoisting
  for (int stage = 0; stage < 2; ++stage) {
    if (stage) __syncthreads();              // stage-0 reads done before overwrite
    for (int i = threadIdx.x; i < 2048; i += 256)
      sB4[i] = wf4[stage * 2048 + i];        // 32 KB of wfrag (L2-resident)
    __syncthreads();

#pragma unroll
    for (int kk = 0; kk < 2; ++kk) {
      int kt = stage * 2 + kk;
      float4 p0 = xa[kt * 8];
      float4 p1 = xa[kt * 8 + 1];
      float4 p2 = xb[kt * 8];
      float4 p3 = xb[kt * 8 + 1];
      float af0[8] = {p0.x, p0.y, p0.z, p0.w, p1.x, p1.y, p1.z, p1.w};
      float af1[8] = {p2.x, p2.y, p2.z, p2.w, p3.x, p3.y, p3.z, p3.w};
      short8 ah0, al0, ah1, al1;
#pragma unroll
      for (int e = 0; e < 8; ++e) {
        unsigned b0 = __float_as_uint(af0[e]);
        ah0[e] = (short)(b0 >> 16);
        float lo0 = af0[e] - __uint_as_float(b0 & 0xFFFF0000u);
        al0[e] = (short)(__float_as_uint(lo0) >> 16);
        unsigned b1_ = __float_as_uint(af1[e]);
        ah1[e] = (short)(b1_ >> 16);
        float lo1 = af1[e] - __uint_as_float(b1_ & 0xFFFF0000u);
        al1[e] = (short)(__float_as_uint(lo1) >> 16);
      }
#pragma unroll
      for (int mat = 0; mat < 2; ++mat) {
#pragma unroll
        for (int jt = 0; jt < 4; ++jt) {
          int unit = ((kk * 2 + mat) * 4 + jt) * 2;   // local unit within stage
          short8 bh = *(const short8*)(sB + unit * 512 + lane * 8);
          short8 bl = *(const short8*)(sB + (unit + 1) * 512 + lane * 8);
          floatx4 c0 = acc0[mat * 4 + jt];
          c0 = __builtin_amdgcn_mfma_f32_16x16x32_bf16(ah0, bh, c0, 0, 0, 0);
          c0 = __builtin_amdgcn_mfma_f32_16x16x32_bf16(ah0, bl, c0, 0, 0, 0);
          c0 = __builtin_amdgcn_mfma_f32_16x16x32_bf16(al0, bh, c0, 0, 0, 0);
          acc0[mat * 4 + jt] = c0;
          floatx4 c1 = acc1[mat * 4 + jt];
          c1 = __builtin_amdgcn_mfma_f32_16x16x32_bf16(ah1, bh, c1, 0, 0, 0);
          c1 = __builtin_amdgcn_mfma_f32_16x16x32_bf16(ah1, bl, c1, 0, 0, 0);
          c1 = __builtin_amdgcn_mfma_f32_16x16x32_bf16(al1, bh, c1, 0, 0, 0);
          acc1[mat * 4 + jt] = c1;
        }
      }
    }
  }

#pragma unroll
  for (int jt = 0; jt < 4; ++jt) {
    int j = jt * 16 + m;
    float bj = b1[j];
    floatx4 cl0 = acc0[jt], cr0 = acc0[4 + jt];
    floatx4 cl1 = acc1[jt], cr1 = acc1[4 + jt];
    if (act0) {
#pragma unroll
      for (int r = 0; r < 4; ++r) {
        int n0 = tile0 * 16 + q * 4 + r;
        xlb[(size_t)n0 * DH + j] = f2bf(cl0[r]);
        xrb[(size_t)n0 * DH + j] = f2bf(cr0[r] + bj);
      }
    }
    if (act1) {
#pragma unroll
      for (int r = 0; r < 4; ++r) {
        int n1 = tile1 * 16 + q * 4 + r;
        xlb[(size_t)n1 * DH + j] = f2bf(cl1[r]);
        xrb[(size_t)n1 * DH + j] = f2bf(cr1[r] + bj);
      }
    }
  }
}

// ---------- radix pass B: per-bucket CSR (row_start + row_end + eidx) ----------
// int4 reads of part (ebeg = b*CAP is 16B-aligned); scalar tail.
__global__ __launch_bounds__(256) void bucket_csr_kernel(
    const int* __restrict__ part, const int* __restrict__ gcur,
    int* __restrict__ row_start, int* __restrict__ row_end,
    int* __restrict__ eidx) {
  int b = blockIdx.x, t = threadIdx.x;
  int ebeg = b * CAP;
  int cnt_b = gcur[b] - ebeg; if (cnt_b > CAP) cnt_b = CAP;
  int eend = ebeg + cnt_b;
  int nvec = cnt_b >> 2;
  const int4* p4 = (const int4*)(part + ebeg);
  int nbase = b << 8;
  int nloc = NN - nbase; if (nloc > 256) nloc = 256;
  __shared__ int cntL[256];
  __shared__ int exclL[256];
  cntL[t] = 0;
  __syncthreads();
  for (int i = t; i < nvec; i += 256) {
    int4 v = p4[i];
    atomicAdd(&cntL[v.x >> 17], 1);
    atomicAdd(&cntL[v.y >> 17], 1);
    atomicAdd(&cntL[v.z >> 17], 1);
    atomicAdd(&cntL[v.w >> 17], 1);
  }
  for (int e = ebeg + (nvec << 2) + t; e < eend; e += 256)
    atomicAdd(&cntL[part[e] >> 17], 1);
  __syncthreads();
  int c = cntL[t];
  exclL[t] = c;
  __syncthreads();
  for (int off = 1; off < 256; off <<= 1) {
    int v = (t >= off) ? exclL[t - off] : 0;
    __syncthreads();
    exclL[t] += v;
    __syncthreads();
  }
  int excl = exclL[t] - c;
  if (t < nloc) {
    row_start[nbase + t] = ebeg + excl;
    row_end[nbase + t]   = ebeg + excl + c;
  }
  cntL[t] = excl;                 // reuse as cursor
  __syncthreads();
  for (int i = t; i < nvec; i += 256) {
    int4 v = p4[i];
    int ve[4] = {v.x, v.y, v.z, v.w};
#pragma unroll
    for (int u = 0; u < 4; ++u) {
      int pos = atomicAdd(&cntL[ve[u] >> 17], 1);
      eidx[ebeg + pos] = ve[u] & 0x1FFFF;
    }
  }
  for (int e = ebeg + (nvec << 2) + t; e < eend; e += 256) {
    int v = part[e];
    int pos = atomicAdd(&cntL[v >> 17], 1);
    eidx[ebeg + pos] = v & 0x1FFFF;
  }
}

// ---------- layer-1 mean aggregation via gather (+relu+root add) ----------
template <bool RELU_ADD>
__global__ __launch_bounds__(256) void gather_kernel(
    const uint4* __restrict__ feat4, const int* __restrict__ row_start,
    const int* __restrict__ row_end, const int* __restrict__ eidx,
    const uint4* __restrict__ xr4, uint4* __restrict__ out4) {
  int t = blockIdx.x * 256 + threadIdx.x;
  int node = t >> 3;
  if (node >= NN) return;
  int fl = t & 7;
  int rs = row_start[node], re = row_end[node];
  float a0 = 0.f, a1 = 0.f, a2 = 0.f, a3 = 0.f;
  float a4 = 0.f, a5 = 0.f, a6 = 0.f, a7 = 0.f;
  int k = rs;
  for (; k + 8 <= re; k += 8) {           // 8 uint4 loads in flight
    uint4 v[8];
#pragma unroll
    for (int u = 0; u < 8; ++u) v[u] = feat4[(size_t)eidx[k + u] * 8 + fl];
#pragma unroll
    for (int u = 0; u < 8; ++u) {
      a0 += bflo(v[u].x); a1 += bfhi(v[u].x);
      a2 += bflo(v[u].y); a3 += bfhi(v[u].y);
      a4 += bflo(v[u].z); a5 += bfhi(v[u].z);
      a6 += bflo(v[u].w); a7 += bfhi(v[u].w);
    }
  }
  for (; k + 2 <= re; k += 2) {
    uint4 v0 = feat4[(size_t)eidx[k] * 8 + fl];
    uint4 v1 = feat4[(size_t)eidx[k + 1] * 8 + fl];
    a0 += bflo(v0.x) + bflo(v1.x); a1 += bfhi(v0.x) + bfhi(v1.x);
    a2 += bflo(v0.y) + bflo(v1.y); a3 += bfhi(v0.y) + bfhi(v1.y);
    a4 += bflo(v0.z) + bflo(v1.z); a5 += bfhi(v0.z) + bfhi(v1.z);
    a6 += bflo(v0.w) + bflo(v1.w); a7 += bfhi(v0.w) + bfhi(v1.w);
  }
  if (k < re) {
    uint4 v = feat4[(size_t)eidx[k] * 8 + fl];
    a0 += bflo(v.x); a1 += bfhi(v.x);
    a2 += bflo(v.y); a3 += bfhi(v.y);
    a4 += bflo(v.z); a5 += bfhi(v.z);
    a6 += bflo(v.w); a7 += bfhi(v.w);
  }
  float inv = 1.0f / fmaxf((float)(re - rs), 1.0f);
  a0 *= inv; a1 *= inv; a2 *= inv; a3 *= inv;
  a4 *= inv; a5 *= inv; a6 *= inv; a7 *= inv;
  if (RELU_ADD) {
    uint4 r = xr4[(size_t)node * 8 + fl];
    a0 = fmaxf(a0 + bflo(r.x), 0.f); a1 = fmaxf(a1 + bfhi(r.x), 0.f);
    a2 = fmaxf(a2 + bflo(r.y), 0.f); a3 = fmaxf(a3 + bfhi(r.y), 0.f);
    a4 = fmaxf(a4 + bflo(r.z), 0.f); a5 = fmaxf(a5 + bfhi(r.z), 0.f);
    a6 = fmaxf(a6 + bflo(r.w), 0.f); a7 = fmaxf(a7 + bfhi(r.w), 0.f);
  }
  uint4 o;
  o.x = pack2(a0, a1);
  o.y = pack2(a2, a3);
  o.z = pack2(a4, a5);
  o.w = pack2(a6, a7);
  out4[(size_t)node * 8 + fl] = o;
}

// ---------- fused layer-2 gather + pool + final matmul: one block per graph ----------
__global__ __launch_bounds__(1024) void gather2_pool_kernel(
    const uint4* __restrict__ feat4,          // hb rows (bf16, 8x uint4/node)
    const int* __restrict__ row_start, const int* __restrict__ row_end,
    const int* __restrict__ eidx,
    const int* __restrict__ gs, const float* __restrict__ W2l,
    const float* __restrict__ W2r, const float* __restrict__ b2,
    float* __restrict__ out) {
  int g = blockIdx.x;
  int start = gs[g], end = gs[g + 1];
  int slot = threadIdx.x >> 3;        // 0..127 node-slot
  int fl   = threadIdx.x & 7;         // 16B feature chunk (feats fl*8..fl*8+7)
  float sm[8], sh[8];
#pragma unroll
  for (int i = 0; i < 8; ++i) { sm[i] = 0.f; sh[i] = 0.f; }

  for (int n = start + slot; n < end; n += 128) {
    int rs = row_start[n], re = row_end[n];
    float a0 = 0.f, a1 = 0.f, a2 = 0.f, a3 = 0.f;
    float a4 = 0.f, a5 = 0.f, a6 = 0.f, a7 = 0.f;
    int k = rs;
    for (; k + 4 <= re; k += 4) {       // 4 loads in flight
      uint4 v[4];
#pragma unroll
      for (int u = 0; u < 4; ++u) v[u] = feat4[(size_t)eidx[k + u] * 8 + fl];
#pragma unroll
      for (int u = 0; u < 4; ++u) {
        a0 += bflo(v[u].x); a1 += bfhi(v[u].x);
        a2 += bflo(v[u].y); a3 += bfhi(v[u].y);
        a4 += bflo(v[u].z); a5 += bfhi(v[u].z);
        a6 += bflo(v[u].w); a7 += bfhi(v[u].w);
      }
    }
    for (; k < re; ++k) {
      uint4 v = feat4[(size_t)eidx[k] * 8 + fl];
      a0 += bflo(v.x); a1 += bfhi(v.x);
      a2 += bflo(v.y); a3 += bfhi(v.y);
      a4 += bflo(v.z); a5 += bfhi(v.z);
      a6 += bflo(v.w); a7 += bfhi(v.w);
    }
    float inv = 1.0f / fmaxf((float)(re - rs), 1.0f);
    sm[0] += a0 * inv; sm[1] += a1 * inv; sm[2] += a2 * inv; sm[3] += a3 * inv;
    sm[4] += a4 * inv; sm[5] += a5 * inv; sm[6] += a6 * inv; sm[7] += a7 * inv;
    uint4 hv = feat4[(size_t)n * 8 + fl];       // root h for the h-sum
    sh[0] += bflo(hv.x); sh[1] += bfhi(hv.x);
    sh[2] += bflo(hv.y); sh[3] += bfhi(hv.y);
    sh[4] += bflo(hv.z); sh[5] += bfhi(hv.z);
    sh[6] += bflo(hv.w); sh[7] += bfhi(hv.w);
  }

  // reduce the 8 node-slot groups inside each wave (lane bits [5:3])
#pragma unroll
  for (int off = 8; off <= 32; off <<= 1) {
#pragma unroll
    for (int i = 0; i < 8; ++i) {
      sm[i] += __shfl_xor(sm[i], off);
      sh[i] += __shfl_xor(sh[i], off);
    }
  }

  __shared__ float redm[16][DH];
  __shared__ float redh[16][DH];
  int wv = threadIdx.x >> 6;
  int lane = threadIdx.x & 63;
  if (lane < 8) {
#pragma unroll
    for (int i = 0; i < 8; ++i) {
      redm[wv][lane * 8 + i] = sm[i];
      redh[wv][lane * 8 + i] = sh[i];
    }
  }
  __syncthreads();
  __shared__ float msL[DH], hsL[DH];
  if (threadIdx.x < DH) {
    float a = 0.f, b = 0.f;
#pragma unroll
    for (int w = 0; w < 16; ++w) { a += redm[w][threadIdx.x]; b += redh[w][threadIdx.x]; }
    msL[threadIdx.x] = a; hsL[threadIdx.x] = b;
  }
  __syncthreads();
  int j = threadIdx.x;
  if (j < DOUT) {
    float n_ = (float)(end - start);
    float acc = 0.f;
#pragma unroll 8
    for (int k = 0; k < DH; ++k)
      acc += msL[k] * W2l[k * DOUT + j] + hsL[k] * W2r[k * DOUT + j];
    out[g * DOUT + j] = (acc + n_ * b2[j]) / fmaxf(n_, 1.0f);
  }
}

extern "C" void kernel_launch(void* const* d_in, const int* in_sizes, int n_in,
                              void* d_out, int out_size, void* d_ws, size_t ws_size,
                              hipStream_t stream) {
  (void)in_sizes; (void)n_in; (void)out_size; (void)ws_size;
  const float* x   = (const float*)d_in[0];
  const float* W1l = (const float*)d_in[1];
  const float* W1r = (const float*)d_in[2];
  const float* b1  = (const float*)d_in[3];
  const float* W2l = (const float*)d_in[4];
  const float* W2r = (const float*)d_in[5];
  const float* b2  = (const float*)d_in[6];
  const int*   ei  = (const int*)d_in[7];
  const int*   batch = (const int*)d_in[8];
  const int* src = ei;            // edge_index[0, :]
  const int* dst = ei + NE;       // edge_index[1, :]
  float* out = (float*)d_out;

  char* ws = (char*)d_ws;
  unsigned short* xlb = (unsigned short*)(ws);            // 12,800,000 B
  unsigned short* hb  = (unsigned short*)(ws + 12800000); // 12,800,000 B
  unsigned short* xrb = (unsigned short*)(ws + 38400000); // 12,800,000 B
  int*  part      = (int*)(ws + 51200000);           //  8,007,680 B (NB*CAP*4)
  int*  gcur      = (int*)(ws + 59300000);           //      1,564 B
  int*  eidx      = (int*)(ws + 60000000);           //  8,007,680 B (padded)
  int*  row_start = (int*)(ws + 83200000);           //    400,000 B
  int*   gs       = (int*)(ws + 83600128);           //      2,052 B
  short* wfrag    = (short*)(ws + 83900032);         //     65,536 B
  int*  row_end   = (int*)(ws + 84000000);           //    400,000 B

  const int gBlocks = (NN * 8 + 255) / 256;          // 3125

  // prep: bucket cursors + weight split + graph bounds (3 tiny block roles)
  prep_kernel<<<3, 256, 0, stream>>>(gcur, W1l, W1r, wfrag, batch, gs);

  // slice-claim partA (int4 edge reads) fused with round-9 proj (2-tile, staged)
  proj_part_kernel<<<PARTB + 782, 256, 0, stream>>>(src, dst, gcur, part,
                                                    x, wfrag, b1, xlb, xrb);
  bucket_csr_kernel<<<NB, 256, 0, stream>>>(part, gcur, row_start, row_end, eidx);

  // layer 1 aggregation (+ relu + root add)
  gather_kernel<true><<<gBlocks, 256, 0, stream>>>(
      (const uint4*)xlb, row_start, row_end, eidx, (const uint4*)xrb, (uint4*)hb);

  // layer 2 aggregation fused with pool + final matmul (one block per graph)
  gather2_pool_kernel<<<NG, 1024, 0, stream>>>(
      (const uint4*)hb, row_start, row_end, eidx, gs, W2l, W2r, b2, out);
}

// Round 12
// 224.111 us; speedup vs baseline: 1.1129x; 1.0683x over previous
//
#include <hip/hip_runtime.h>

#define NN   100000
#define NE   1600000
#define DIN  128
#define DH   64
#define DOUT 128
#define NG   512

#define NB    391    // dst buckets of 256 nodes: ceil(NN/256)
#define PARTB 250    // partA blocks
#define EPB   6400   // edges per partA block (= NE/250; 16B-aligned slices)
#define CAP   5120   // padded bucket capacity (verified sufficient rounds 8-11)

typedef short short8 __attribute__((ext_vector_type(8)));
typedef float floatx4 __attribute__((ext_vector_type(4)));

__device__ __forceinline__ unsigned short f2bf(float f) {
  unsigned b = __float_as_uint(f);
  b += 0x7FFF + ((b >> 16) & 1);          // round-to-nearest-even
  return (unsigned short)(b >> 16);
}
__device__ __forceinline__ float bflo(unsigned u) {   // low 16 bits -> float
  return __uint_as_float(u << 16);
}
__device__ __forceinline__ float bfhi(unsigned u) {   // high 16 bits -> float
  return __uint_as_float(u & 0xFFFF0000u);
}
__device__ __forceinline__ unsigned pack2(float a, float b) {
  return (unsigned)f2bf(a) | ((unsigned)f2bf(b) << 16);
}

// ---------- prep: cursor init (block 0) + weight split (1) + graph bounds (2) ----------
__global__ __launch_bounds__(256) void prep_kernel(
    int* __restrict__ gcur,
    const float* __restrict__ W1l, const float* __restrict__ W1r,
    short* __restrict__ wfrag, const int* __restrict__ batch,
    int* __restrict__ gs) {
  int b = blockIdx.x;
  if (b == 0) {                       // --- bucket cursors: base of each region ---
    for (int i = threadIdx.x; i < NB; i += 256) gcur[i] = i * CAP;
  } else if (b == 1) {                // --- weight split ---
    for (int i = threadIdx.x; i < DIN * DH; i += 256) {
      int k = i >> 6, n = i & 63;
      int kt = k >> 5, kin = k & 31;
      int lane = ((kin >> 3) << 4) | (n & 15);
      int j8 = kin & 7;
      int jt = n >> 4;
      float wl = W1l[i], wr = W1r[i];
      unsigned bl_ = __float_as_uint(wl);
      unsigned br_ = __float_as_uint(wr);
      short hl = (short)(bl_ >> 16);
      short hr = (short)(br_ >> 16);
      float rl = wl - __uint_as_float(bl_ & 0xFFFF0000u);
      float rr = wr - __uint_as_float(br_ & 0xFFFF0000u);
      short ll = (short)(__float_as_uint(rl) >> 16);
      short lr = (short)(__float_as_uint(rr) >> 16);
      int base0 = (((kt * 2 + 0) * 4 + jt) * 2) * 512 + lane * 8 + j8;
      int base1 = (((kt * 2 + 1) * 4 + jt) * 2) * 512 + lane * 8 + j8;
      wfrag[base0]       = hl;
      wfrag[base0 + 512] = ll;
      wfrag[base1]       = hr;
      wfrag[base1 + 512] = lr;
    }
  } else {                            // --- graph boundaries ---
    for (int g = threadIdx.x; g <= NG; g += 256) {
      if (g == NG) { gs[NG] = NN; continue; }
      int lo = 0, hi = NN;
      while (lo < hi) {
        int mid = (lo + hi) >> 1;
        if (batch[mid] < g) lo = mid + 1; else hi = mid;
      }
      gs[g] = lo;
    }
  }
}

// ---------- fused: slice-claim partA (blocks 0..249) + proj MFMA (250..1031) ----------
// (verified round 9/11 structure)
__global__ __launch_bounds__(256, 4) void proj_part_kernel(
    const int* __restrict__ src, const int* __restrict__ dst,
    int* __restrict__ gcur, int* __restrict__ part,
    const float* __restrict__ x, const short* __restrict__ wfrag,
    const float* __restrict__ b1, unsigned short* __restrict__ xlb,
    unsigned short* __restrict__ xrb) {
  __shared__ short sB[16384];   // 32 KB (partA aliases as 3 int arrays of NB)
  if (blockIdx.x < PARTB) {
    int* hist  = (int*)sB;            // [NB]
    int* base_ = hist + NB;           // [NB]
    int* lcur  = hist + 2 * NB;       // [NB]   (4.7 KB total)
    for (int i = threadIdx.x; i < NB; i += 256) hist[i] = 0;
    __syncthreads();
    int start = blockIdx.x * EPB;
    const int4* d4 = (const int4*)(dst + start);   // 16B-aligned
    const int4* s4 = (const int4*)(src + start);
    for (int i = threadIdx.x; i < EPB / 4; i += 256) {
      int4 d = d4[i];
      atomicAdd(&hist[d.x >> 8], 1);
      atomicAdd(&hist[d.y >> 8], 1);
      atomicAdd(&hist[d.z >> 8], 1);
      atomicAdd(&hist[d.w >> 8], 1);
    }
    __syncthreads();
    for (int i = threadIdx.x; i < NB; i += 256) {
      base_[i] = atomicAdd(&gcur[i], hist[i]);     // 1 global atomic / bucket
      lcur[i] = 0;
    }
    __syncthreads();
    for (int i = threadIdx.x; i < EPB / 4; i += 256) {
      int4 d = d4[i];
      int4 s = s4[i];
      int de[4] = {d.x, d.y, d.z, d.w};
      int se[4] = {s.x, s.y, s.z, s.w};
#pragma unroll
      for (int u = 0; u < 4; ++u) {
        int bkt = de[u] >> 8;
        int pos = base_[bkt] + atomicAdd(&lcur[bkt], 1);  // LDS atomic
        if (pos < (bkt + 1) * CAP)                        // overflow guard
          part[pos] = ((de[u] & 255) << 17) | se[u];
      }
    }
    return;
  }
  // --- proj: xl(bf16)=x@W1l, xr(bf16)=x@W1r+b1 (round-9 verified structure) ---
  int wave = threadIdx.x >> 6;
  int lane = threadIdx.x & 63;
  int m = lane & 15, q = lane >> 4;
  int tpair = (blockIdx.x - PARTB) * 4 + wave;
  int tile0 = tpair * 2, tile1 = tile0 + 1;
  bool act0 = tile0 < 6250;
  bool act1 = tile1 < 6250;
  int t0c = act0 ? tile0 : 6249;   // clamp: tail waves compute garbage, skip stores
  int t1c = act1 ? tile1 : 6249;

  int r0 = t0c * 16 + m;
  int r1 = t1c * 16 + m;
  const float4* xa = (const float4*)x + (size_t)r0 * 32 + q * 2;
  const float4* xb = (const float4*)x + (size_t)r1 * 32 + q * 2;

  floatx4 acc0[8], acc1[8];
#pragma unroll
  for (int a = 0; a < 8; ++a) {
    acc0[a] = (floatx4){0.f, 0.f, 0.f, 0.f};
    acc1[a] = (floatx4){0.f, 0.f, 0.f, 0.f};
  }

  const float4* wf4 = (const float4*)wfrag;
  float4* sB4 = (float4*)sB;

#pragma unroll 1              // keep rolled: bounds VGPR, prevents load hoisting
  for (int stage = 0; stage < 2; ++stage) {
    if (stage) __syncthreads();              // stage-0 reads done before overwrite
    for (int i = threadIdx.x; i < 2048; i += 256)
      sB4[i] = wf4[stage * 2048 + i];        // 32 KB of wfrag (L2-resident)
    __syncthreads();

#pragma unroll
    for (int kk = 0; kk < 2; ++kk) {
      int kt = stage * 2 + kk;
      float4 p0 = xa[kt * 8];
      float4 p1 = xa[kt * 8 + 1];
      float4 p2 = xb[kt * 8];
      float4 p3 = xb[kt * 8 + 1];
      float af0[8] = {p0.x, p0.y, p0.z, p0.w, p1.x, p1.y, p1.z, p1.w};
      float af1[8] = {p2.x, p2.y, p2.z, p2.w, p3.x, p3.y, p3.z, p3.w};
      short8 ah0, al0, ah1, al1;
#pragma unroll
      for (int e = 0; e < 8; ++e) {
        unsigned b0 = __float_as_uint(af0[e]);
        ah0[e] = (short)(b0 >> 16);
        float lo0 = af0[e] - __uint_as_float(b0 & 0xFFFF0000u);
        al0[e] = (short)(__float_as_uint(lo0) >> 16);
        unsigned b1_ = __float_as_uint(af1[e]);
        ah1[e] = (short)(b1_ >> 16);
        float lo1 = af1[e] - __uint_as_float(b1_ & 0xFFFF0000u);
        al1[e] = (short)(__float_as_uint(lo1) >> 16);
      }
#pragma unroll
      for (int mat = 0; mat < 2; ++mat) {
#pragma unroll
        for (int jt = 0; jt < 4; ++jt) {
          int unit = ((kk * 2 + mat) * 4 + jt) * 2;   // local unit within stage
          short8 bh = *(const short8*)(sB + unit * 512 + lane * 8);
          short8 bl = *(const short8*)(sB + (unit + 1) * 512 + lane * 8);
          floatx4 c0 = acc0[mat * 4 + jt];
          c0 = __builtin_amdgcn_mfma_f32_16x16x32_bf16(ah0, bh, c0, 0, 0, 0);
          c0 = __builtin_amdgcn_mfma_f32_16x16x32_bf16(ah0, bl, c0, 0, 0, 0);
          c0 = __builtin_amdgcn_mfma_f32_16x16x32_bf16(al0, bh, c0, 0, 0, 0);
          acc0[mat * 4 + jt] = c0;
          floatx4 c1 = acc1[mat * 4 + jt];
          c1 = __builtin_amdgcn_mfma_f32_16x16x32_bf16(ah1, bh, c1, 0, 0, 0);
          c1 = __builtin_amdgcn_mfma_f32_16x16x32_bf16(ah1, bl, c1, 0, 0, 0);
          c1 = __builtin_amdgcn_mfma_f32_16x16x32_bf16(al1, bh, c1, 0, 0, 0);
          acc1[mat * 4 + jt] = c1;
        }
      }
    }
  }

#pragma unroll
  for (int jt = 0; jt < 4; ++jt) {
    int j = jt * 16 + m;
    float bj = b1[j];
    floatx4 cl0 = acc0[jt], cr0 = acc0[4 + jt];
    floatx4 cl1 = acc1[jt], cr1 = acc1[4 + jt];
    if (act0) {
#pragma unroll
      for (int r = 0; r < 4; ++r) {
        int n0 = tile0 * 16 + q * 4 + r;
        xlb[(size_t)n0 * DH + j] = f2bf(cl0[r]);
        xrb[(size_t)n0 * DH + j] = f2bf(cr0[r] + bj);
      }
    }
    if (act1) {
#pragma unroll
      for (int r = 0; r < 4; ++r) {
        int n1 = tile1 * 16 + q * 4 + r;
        xlb[(size_t)n1 * DH + j] = f2bf(cl1[r]);
        xrb[(size_t)n1 * DH + j] = f2bf(cr1[r] + bj);
      }
    }
  }
}

// ---------- fused CSR + layer-1 gather: one block per bucket, 1024 threads ----------
// Block b builds bucket b's CSR (LDS-resident eidx slice), writes eidx/row bounds
// to global only for gather2's use, then immediately gathers layer-1 aggregation
// for its own 256 nodes from the LDS eidx — no kernel boundary, no global eidx
// round-trip for layer 1.
__global__ __launch_bounds__(1024) void csr_gather1_kernel(
    const int* __restrict__ part, const int* __restrict__ gcur,
    int* __restrict__ row_start, int* __restrict__ row_end,
    int* __restrict__ eidx,
    const uint4* __restrict__ xlb4, const uint4* __restrict__ xrb4,
    uint4* __restrict__ hb4) {
  int b = blockIdx.x, t = threadIdx.x;
  int ebeg = b * CAP;
  int cnt_b = gcur[b] - ebeg; if (cnt_b > CAP) cnt_b = CAP;
  int nbase = b << 8;
  int nloc = NN - nbase; if (nloc > 256) nloc = 256;

  __shared__ int cntL[256];     // counts, then scatter cursor
  __shared__ int lsA[256];      // scan temp, then local row start
  __shared__ int leA[256];      // local row end
  __shared__ int eidxL[CAP];    // 20 KB LDS-resident eidx slice

  if (t < 256) cntL[t] = 0;
  __syncthreads();

  // --- histogram (int4 reads, 1024 threads) ---
  int nvec = cnt_b >> 2;
  const int4* p4 = (const int4*)(part + ebeg);     // ebeg = b*CAP, 16B-aligned
  for (int i = t; i < nvec; i += 1024) {
    int4 v = p4[i];
    atomicAdd(&cntL[v.x >> 17], 1);
    atomicAdd(&cntL[v.y >> 17], 1);
    atomicAdd(&cntL[v.z >> 17], 1);
    atomicAdd(&cntL[v.w >> 17], 1);
  }
  for (int e = (nvec << 2) + t; e < cnt_b; e += 1024)
    atomicAdd(&cntL[part[ebeg + e] >> 17], 1);
  __syncthreads();

  // --- exclusive scan over 256 node-counts (threads <256 active, all at barriers) ---
  int c = 0;
  if (t < 256) { c = cntL[t]; lsA[t] = c; }
  __syncthreads();
  for (int off = 1; off < 256; off <<= 1) {
    int v = 0;
    if (t < 256 && t >= off) v = lsA[t - off];
    __syncthreads();
    if (t < 256) lsA[t] += v;
    __syncthreads();
  }
  if (t < 256) {
    int excl = lsA[t] - c;
    lsA[t] = excl;
    leA[t] = excl + c;
    if (t < nloc) {                        // global bounds for gather2 only
      row_start[nbase + t] = ebeg + excl;
      row_end[nbase + t]   = ebeg + excl + c;
    }
    cntL[t] = excl;                        // reuse as scatter cursor
  }
  __syncthreads();

  // --- scatter: part -> LDS eidx (+ global eidx for gather2) ---
  for (int i = t; i < nvec; i += 1024) {
    int4 v = p4[i];
    int ve[4] = {v.x, v.y, v.z, v.w};
#pragma unroll
    for (int u = 0; u < 4; ++u) {
      int pos = atomicAdd(&cntL[ve[u] >> 17], 1);
      int s = ve[u] & 0x1FFFF;
      eidxL[pos] = s;
      eidx[ebeg + pos] = s;
    }
  }
  for (int e = (nvec << 2) + t; e < cnt_b; e += 1024) {
    int v = part[ebeg + e];
    int pos = atomicAdd(&cntL[v >> 17], 1);
    int s = v & 0x1FFFF;
    eidxL[pos] = s;
    eidx[ebeg + pos] = s;
  }
  __syncthreads();

  // --- layer-1 gather for own bucket: 8 lanes/node, 128 nodes/pass, 2 passes ---
  int fl = t & 7;
  for (int pass = 0; pass < 2; ++pass) {
    int nl = (t >> 3) + (pass << 7);
    if (nl >= nloc) continue;              // no barriers below — safe
    int rs = lsA[nl], re = leA[nl];
    float a0 = 0.f, a1 = 0.f, a2 = 0.f, a3 = 0.f;
    float a4 = 0.f, a5 = 0.f, a6 = 0.f, a7 = 0.f;
    int k = rs;
    for (; k + 8 <= re; k += 8) {          // 8 uint4 loads in flight
      uint4 v[8];
#pragma unroll
      for (int u = 0; u < 8; ++u) v[u] = xlb4[(size_t)eidxL[k + u] * 8 + fl];
#pragma unroll
      for (int u = 0; u < 8; ++u) {
        a0 += bflo(v[u].x); a1 += bfhi(v[u].x);
        a2 += bflo(v[u].y); a3 += bfhi(v[u].y);
        a4 += bflo(v[u].z); a5 += bfhi(v[u].z);
        a6 += bflo(v[u].w); a7 += bfhi(v[u].w);
      }
    }
    for (; k + 2 <= re; k += 2) {
      uint4 v0 = xlb4[(size_t)eidxL[k] * 8 + fl];
      uint4 v1 = xlb4[(size_t)eidxL[k + 1] * 8 + fl];
      a0 += bflo(v0.x) + bflo(v1.x); a1 += bfhi(v0.x) + bfhi(v1.x);
      a2 += bflo(v0.y) + bflo(v1.y); a3 += bfhi(v0.y) + bfhi(v1.y);
      a4 += bflo(v0.z) + bflo(v1.z); a5 += bfhi(v0.z) + bfhi(v1.z);
      a6 += bflo(v0.w) + bflo(v1.w); a7 += bfhi(v0.w) + bfhi(v1.w);
    }
    if (k < re) {
      uint4 v = xlb4[(size_t)eidxL[k] * 8 + fl];
      a0 += bflo(v.x); a1 += bfhi(v.x);
      a2 += bflo(v.y); a3 += bfhi(v.y);
      a4 += bflo(v.z); a5 += bfhi(v.z);
      a6 += bflo(v.w); a7 += bfhi(v.w);
    }
    float inv = 1.0f / fmaxf((float)(re - rs), 1.0f);
    a0 *= inv; a1 *= inv; a2 *= inv; a3 *= inv;
    a4 *= inv; a5 *= inv; a6 *= inv; a7 *= inv;
    int node = nbase + nl;
    uint4 r = xrb4[(size_t)node * 8 + fl];       // + root, relu
    a0 = fmaxf(a0 + bflo(r.x), 0.f); a1 = fmaxf(a1 + bfhi(r.x), 0.f);
    a2 = fmaxf(a2 + bflo(r.y), 0.f); a3 = fmaxf(a3 + bfhi(r.y), 0.f);
    a4 = fmaxf(a4 + bflo(r.z), 0.f); a5 = fmaxf(a5 + bfhi(r.z), 0.f);
    a6 = fmaxf(a6 + bflo(r.w), 0.f); a7 = fmaxf(a7 + bfhi(r.w), 0.f);
    uint4 o;
    o.x = pack2(a0, a1);
    o.y = pack2(a2, a3);
    o.z = pack2(a4, a5);
    o.w = pack2(a6, a7);
    hb4[(size_t)node * 8 + fl] = o;
  }
}

// ---------- fused layer-2 gather + pool + final matmul: one block per graph ----------
__global__ __launch_bounds__(1024) void gather2_pool_kernel(
    const uint4* __restrict__ feat4,          // hb rows (bf16, 8x uint4/node)
    const int* __restrict__ row_start, const int* __restrict__ row_end,
    const int* __restrict__ eidx,
    const int* __restrict__ gs, const float* __restrict__ W2l,
    const float* __restrict__ W2r, const float* __restrict__ b2,
    float* __restrict__ out) {
  int g = blockIdx.x;
  int start = gs[g], end = gs[g + 1];
  int slot = threadIdx.x >> 3;        // 0..127 node-slot
  int fl   = threadIdx.x & 7;         // 16B feature chunk (feats fl*8..fl*8+7)
  float sm[8], sh[8];
#pragma unroll
  for (int i = 0; i < 8; ++i) { sm[i] = 0.f; sh[i] = 0.f; }

  for (int n = start + slot; n < end; n += 128) {
    int rs = row_start[n], re = row_end[n];
    float a0 = 0.f, a1 = 0.f, a2 = 0.f, a3 = 0.f;
    float a4 = 0.f, a5 = 0.f, a6 = 0.f, a7 = 0.f;
    int k = rs;
    for (; k + 4 <= re; k += 4) {       // 4 loads in flight
      uint4 v[4];
#pragma unroll
      for (int u = 0; u < 4; ++u) v[u] = feat4[(size_t)eidx[k + u] * 8 + fl];
#pragma unroll
      for (int u = 0; u < 4; ++u) {
        a0 += bflo(v[u].x); a1 += bfhi(v[u].x);
        a2 += bflo(v[u].y); a3 += bfhi(v[u].y);
        a4 += bflo(v[u].z); a5 += bfhi(v[u].z);
        a6 += bflo(v[u].w); a7 += bfhi(v[u].w);
      }
    }
    for (; k < re; ++k) {
      uint4 v = feat4[(size_t)eidx[k] * 8 + fl];
      a0 += bflo(v.x); a1 += bfhi(v.x);
      a2 += bflo(v.y); a3 += bfhi(v.y);
      a4 += bflo(v.z); a5 += bfhi(v.z);
      a6 += bflo(v.w); a7 += bfhi(v.w);
    }
    float inv = 1.0f / fmaxf((float)(re - rs), 1.0f);
    sm[0] += a0 * inv; sm[1] += a1 * inv; sm[2] += a2 * inv; sm[3] += a3 * inv;
    sm[4] += a4 * inv; sm[5] += a5 * inv; sm[6] += a6 * inv; sm[7] += a7 * inv;
    uint4 hv = feat4[(size_t)n * 8 + fl];       // root h for the h-sum
    sh[0] += bflo(hv.x); sh[1] += bfhi(hv.x);
    sh[2] += bflo(hv.y); sh[3] += bfhi(hv.y);
    sh[4] += bflo(hv.z); sh[5] += bfhi(hv.z);
    sh[6] += bflo(hv.w); sh[7] += bfhi(hv.w);
  }

  // reduce the 8 node-slot groups inside each wave (lane bits [5:3])
#pragma unroll
  for (int off = 8; off <= 32; off <<= 1) {
#pragma unroll
    for (int i = 0; i < 8; ++i) {
      sm[i] += __shfl_xor(sm[i], off);
      sh[i] += __shfl_xor(sh[i], off);
    }
  }

  __shared__ float redm[16][DH];
  __shared__ float redh[16][DH];
  int wv = threadIdx.x >> 6;
  int lane = threadIdx.x & 63;
  if (lane < 8) {
#pragma unroll
    for (int i = 0; i < 8; ++i) {
      redm[wv][lane * 8 + i] = sm[i];
      redh[wv][lane * 8 + i] = sh[i];
    }
  }
  __syncthreads();
  __shared__ float msL[DH], hsL[DH];
  if (threadIdx.x < DH) {
    float a = 0.f, b = 0.f;
#pragma unroll
    for (int w = 0; w < 16; ++w) { a += redm[w][threadIdx.x]; b += redh[w][threadIdx.x]; }
    msL[threadIdx.x] = a; hsL[threadIdx.x] = b;
  }
  __syncthreads();
  int j = threadIdx.x;
  if (j < DOUT) {
    float n_ = (float)(end - start);
    float acc = 0.f;
#pragma unroll 8
    for (int k = 0; k < DH; ++k)
      acc += msL[k] * W2l[k * DOUT + j] + hsL[k] * W2r[k * DOUT + j];
    out[g * DOUT + j] = (acc + n_ * b2[j]) / fmaxf(n_, 1.0f);
  }
}

extern "C" void kernel_launch(void* const* d_in, const int* in_sizes, int n_in,
                              void* d_out, int out_size, void* d_ws, size_t ws_size,
                              hipStream_t stream) {
  (void)in_sizes; (void)n_in; (void)out_size; (void)ws_size;
  const float* x   = (const float*)d_in[0];
  const float* W1l = (const float*)d_in[1];
  const float* W1r = (const float*)d_in[2];
  const float* b1  = (const float*)d_in[3];
  const float* W2l = (const float*)d_in[4];
  const float* W2r = (const float*)d_in[5];
  const float* b2  = (const float*)d_in[6];
  const int*   ei  = (const int*)d_in[7];
  const int*   batch = (const int*)d_in[8];
  const int* src = ei;            // edge_index[0, :]
  const int* dst = ei + NE;       // edge_index[1, :]
  float* out = (float*)d_out;

  char* ws = (char*)d_ws;
  unsigned short* xlb = (unsigned short*)(ws);            // 12,800,000 B
  unsigned short* hb  = (unsigned short*)(ws + 12800000); // 12,800,000 B
  unsigned short* xrb = (unsigned short*)(ws + 38400000); // 12,800,000 B
  int*  part      = (int*)(ws + 51200000);           //  8,007,680 B (NB*CAP*4)
  int*  gcur      = (int*)(ws + 59300000);           //      1,564 B
  int*  eidx      = (int*)(ws + 60000000);           //  8,007,680 B (padded)
  int*  row_start = (int*)(ws + 83200000);           //    400,000 B
  int*   gs       = (int*)(ws + 83600128);           //      2,052 B
  short* wfrag    = (short*)(ws + 83900032);         //     65,536 B
  int*  row_end   = (int*)(ws + 84000000);           //    400,000 B

  // prep: bucket cursors + weight split + graph bounds (3 tiny block roles)
  prep_kernel<<<3, 256, 0, stream>>>(gcur, W1l, W1r, wfrag, batch, gs);

  // slice-claim partA fused with proj (round-11 verified)
  proj_part_kernel<<<PARTB + 782, 256, 0, stream>>>(src, dst, gcur, part,
                                                    x, wfrag, b1, xlb, xrb);

  // fused per-bucket CSR build + layer-1 gather (LDS-resident eidx)
  csr_gather1_kernel<<<NB, 1024, 0, stream>>>(
      part, gcur, row_start, row_end, eidx,
      (const uint4*)xlb, (const uint4*)xrb, (uint4*)hb);

  // layer 2 aggregation fused with pool + final matmul (one block per graph)
  gather2_pool_kernel<<<NG, 1024, 0, stream>>>(
      (const uint4*)hb, row_start, row_end, eidx, gs, W2l, W2r, b2, out);
}